// Round 5
// baseline (4134.326 us; speedup 1.0000x reference)
//
#include <hip/hip_runtime.h>

// ---------- types ----------
typedef __attribute__((ext_vector_type(8))) short bf16x8;   // 8 bf16 in 4 VGPRs
typedef __attribute__((ext_vector_type(4))) float f32x4;

// ---------- bf16 helpers (RNE, bit-level) ----------
__device__ __forceinline__ short f2bf(float f) {
    union { float f; unsigned u; } v; v.f = f;
    unsigned r = v.u + 0x7fffu + ((v.u >> 16) & 1u);
    return (short)(r >> 16);
}
__device__ __forceinline__ float bf2f(short s) {
    union { unsigned u; float f; } v; v.u = ((unsigned)(unsigned short)s) << 16;
    return v.f;
}
__device__ __forceinline__ unsigned pack2(float x, float y) {
    return (unsigned)(unsigned short)f2bf(x) | ((unsigned)(unsigned short)f2bf(y) << 16);
}
__device__ __forceinline__ uint4 pack8(float4 a, float4 b) {
    return make_uint4(pack2(a.x, a.y), pack2(a.z, a.w), pack2(b.x, b.y), pack2(b.z, b.w));
}
__device__ __forceinline__ float tanh_fast(float x) {
    float e = __expf(2.f * x);
    return 1.f - 2.f / (e + 1.f);
}
__device__ __forceinline__ uint4 tanh8(uint4 zv) {
    const unsigned* zp = (const unsigned*)&zv;
    uint4 out;
    unsigned* op = (unsigned*)&out;
    #pragma unroll
    for (int j = 0; j < 4; j++) {
        float lo = tanh_fast(bf2f((short)(zp[j] & 0xffffu)));
        float hi = tanh_fast(bf2f((short)(zp[j] >> 16)));
        op[j] = pack2(lo, hi);
    }
    return out;
}

// async global -> LDS, 16B per lane (dest = wave-uniform base + lane*16)
__device__ __forceinline__ void gll16(const void* gp, void* lp) {
    __builtin_amdgcn_global_load_lds(
        (__attribute__((address_space(1))) void*)gp,
        (__attribute__((address_space(3))) void*)lp, 16, 0, 0);
}

// ---------- prep: fp32 [1024][1024] -> bf16 ----------
__global__ __launch_bounds__(256) void pack_w(const float* __restrict__ src,
                                              short* __restrict__ dst) {
    int idx = (blockIdx.x * 256 + threadIdx.x) * 8;
    float4 f0 = ((const float4*)(src + idx))[0];
    float4 f1 = ((const float4*)(src + idx))[1];
    *(uint4*)(dst + idx) = pack8(f0, f1);
}

__global__ void prep_b(const float* __restrict__ b_ih, const float* __restrict__ b_hh,
                       float* __restrict__ bsum) {
    int n = threadIdx.x;
    bsum[n] = b_ih[n] + b_hh[n];
}

// ---------- convert av fp32 [b][t][k] -> bf16 X[t*1024+b][k] (scan-row order) ----------
__global__ __launch_bounds__(256) void conv_av(const float* __restrict__ av,
                                               short* __restrict__ X) {
    size_t e = ((size_t)blockIdx.x * 256 + threadIdx.x) * 8;
    size_t row = e >> 10;                 // b*64 + t
    int k = (int)(e & 1023);
    int b = (int)(row >> 6), t = (int)(row & 63);
    float4 f0 = *(const float4*)(av + e);
    float4 f1 = *(const float4*)(av + e + 4);
    *(uint4*)(X + ((size_t)t * 1024 + b) * 1024 + k) = pack8(f0, f1);
}

// ---------- zgemm2: m97-structure bf16 GEMM, both-sides XOR swizzle (verified R3/R4) ----------
__global__ __launch_bounds__(256) void zgemm2(const short* __restrict__ X,
                                              const short* __restrict__ Wih,
                                              const float* __restrict__ bsum,
                                              short* __restrict__ Z) {
    __shared__ short smem[16384];         // 32KB: As[128][64] + Bs[128][64]; epilogue: C[128][128]
    short* As = smem;
    short* Bs = smem + 8192;

    const int tid = threadIdx.x, lane = tid & 63, wave = tid >> 6;
    const int wm = wave >> 1, wn = wave & 1;
    const int m0 = blockIdx.y * 128, n0 = blockIdx.x * 128;

    const int srow = wave * 32 + (lane >> 3);
    const int scol = ((lane & 7) ^ (lane >> 3)) * 8;
    const short* asrc = X   + (size_t)(m0 + srow) * 1024 + scol;
    const short* bsrc = Wih + (size_t)(n0 + srow) * 1024 + scol;
    char* aldst = (char*)As + wave * 4096;
    char* bldst = (char*)Bs + wave * 4096;

    f32x4 acc[4][4];
    #pragma unroll
    for (int i = 0; i < 4; i++)
        #pragma unroll
        for (int j = 0; j < 4; j++) acc[i][j] = (f32x4)0.0f;

    const int r = lane & 15, q = lane >> 4;

    for (int kt = 0; kt < 16; ++kt) {
        const int kbase = kt * 64;
        #pragma unroll
        for (int i = 0; i < 4; i++) {
            gll16(asrc + kbase + i * 8192, aldst + i * 1024);
            gll16(bsrc + kbase + i * 8192, bldst + i * 1024);
        }
        __syncthreads();

        #pragma unroll
        for (int ks = 0; ks < 2; ++ks) {
            bf16x8 af[4], bfr[4];
            #pragma unroll
            for (int i = 0; i < 4; i++) {
                int ar = wm * 64 + i * 16 + r;
                int br = wn * 64 + i * 16 + r;
                af[i]  = *(const bf16x8*)&As[ar * 64 + (((ks * 4 + q) ^ (r & 7)) << 3)];
                bfr[i] = *(const bf16x8*)&Bs[br * 64 + (((ks * 4 + q) ^ (r & 7)) << 3)];
            }
            #pragma unroll
            for (int i = 0; i < 4; i++)
                #pragma unroll
                for (int j = 0; j < 4; j++)
                    acc[i][j] = __builtin_amdgcn_mfma_f32_16x16x32_bf16(af[i], bfr[j], acc[i][j], 0, 0, 0);
        }
        __syncthreads();
    }

    short* Csh = smem;    // [128][128] shorts = 32KB
    #pragma unroll
    for (int j = 0; j < 4; j++) {
        int colc = wn * 64 + j * 16 + r;
        float bs = bsum[n0 + colc];
        int chunkc = colc >> 3, rem = colc & 7;
        #pragma unroll
        for (int i = 0; i < 4; i++) {
            int rowb = wm * 64 + i * 16 + q * 4;
            #pragma unroll
            for (int rr = 0; rr < 4; rr++) {
                int row = rowb + rr;
                int sc = ((chunkc ^ (row & 7)) << 3) | rem;
                Csh[row * 128 + sc] = f2bf(acc[i][j][rr] + bs);
            }
        }
    }
    __syncthreads();
    #pragma unroll
    for (int p = 0; p < 8; p++) {
        int row = p * 16 + (tid >> 4);
        int chunk = tid & 15;
        int rc = chunk ^ (row & 7);
        uint4 v = *(const uint4*)&Csh[row * 128 + rc * 8];
        *(uint4*)(Z + (size_t)(m0 + row) * 1024 + n0 + chunk * 8) = v;
    }
}

// ---------- fallback zgemm (used only if ws too small for X) ----------
#define ZLDK 72

__global__ __launch_bounds__(256) void zgemm(const float* __restrict__ av,
                                             const short* __restrict__ Wih,
                                             const float* __restrict__ bsum,
                                             short* __restrict__ Z) {
    __shared__ short As[128 * ZLDK];
    __shared__ short Bs[128 * ZLDK];

    const int tid = threadIdx.x, lane = tid & 63, wave = tid >> 6;
    const int wm = wave >> 1, wn = wave & 1;
    const int m0 = blockIdx.y * 128, n0 = blockIdx.x * 128;
    const int srow = tid >> 1, scol = (tid & 1) * 32;

    const int gr = m0 + srow;
    const int tt = gr >> 10, bb = gr & 1023;
    const float* asrc = av + ((size_t)bb * 64 + tt) * 1024 + scol;
    const short* bsrc = Wih + (size_t)(n0 + srow) * 1024 + scol;

    uint4 ra[4], rb[4];
    #pragma unroll
    for (int j = 0; j < 4; j++) {
        float4 f0 = *(const float4*)(asrc + 8 * j);
        float4 f1 = *(const float4*)(asrc + 8 * j + 4);
        ra[j] = pack8(f0, f1);
        rb[j] = *(const uint4*)(bsrc + 8 * j);
    }

    f32x4 acc[4][4];
    #pragma unroll
    for (int i = 0; i < 4; i++)
        #pragma unroll
        for (int j = 0; j < 4; j++) acc[i][j] = (f32x4)0.0f;

    const int r = lane & 15, q = lane >> 4;
    const int koff = q * 8;

    for (int kt = 0; kt < 16; ++kt) {
        #pragma unroll
        for (int j = 0; j < 4; j++) {
            *(uint4*)&As[srow * ZLDK + scol + 8 * j] = ra[j];
            *(uint4*)&Bs[srow * ZLDK + scol + 8 * j] = rb[j];
        }
        __syncthreads();

        if (kt < 15) {
            int k = (kt + 1) * 64;
            #pragma unroll
            for (int j = 0; j < 4; j++) {
                float4 f0 = *(const float4*)(asrc + k + 8 * j);
                float4 f1 = *(const float4*)(asrc + k + 8 * j + 4);
                ra[j] = pack8(f0, f1);
                rb[j] = *(const uint4*)(bsrc + k + 8 * j);
            }
        }

        #pragma unroll
        for (int ks = 0; ks < 2; ++ks) {
            bf16x8 af[4], bfr[4];
            #pragma unroll
            for (int i = 0; i < 4; i++) {
                af[i]  = *(const bf16x8*)&As[(wm * 64 + i * 16 + r) * ZLDK + ks * 32 + koff];
                bfr[i] = *(const bf16x8*)&Bs[(wn * 64 + i * 16 + r) * ZLDK + ks * 32 + koff];
            }
            #pragma unroll
            for (int i = 0; i < 4; i++)
                #pragma unroll
                for (int j = 0; j < 4; j++)
                    acc[i][j] = __builtin_amdgcn_mfma_f32_16x16x32_bf16(af[i], bfr[j], acc[i][j], 0, 0, 0);
        }
        __syncthreads();
    }

    #pragma unroll
    for (int j = 0; j < 4; j++) {
        int n = n0 + wn * 64 + j * 16 + r;
        float bs = bsum[n];
        #pragma unroll
        for (int i = 0; i < 4; i++) {
            int mb = m0 + wm * 64 + i * 16 + q * 4;
            #pragma unroll
            for (int rr = 0; rr < 4; rr++)
                Z[(size_t)(mb + rr) * 1024 + n] = f2bf(acc[i][j][rr] + bs);
        }
    }
}

// ---------- t=0 standalone (fallback path) ----------
__global__ __launch_bounds__(256) void t0_kernel(const short* __restrict__ Z,
                                                 short* __restrict__ h) {
    int idx = (blockIdx.x * 256 + threadIdx.x) * 8;
    *(uint4*)(h + idx) = tanh8(*(const uint4*)(Z + idx));
}

// ---------- RNN step (fallback path) ----------
#define SLDK 136

__global__ __launch_bounds__(512) void step_kernel(const short* __restrict__ Whh,
                                                   const short* __restrict__ Z,
                                                   const short* __restrict__ h_in,
                                                   short* __restrict__ h_out, int t) {
    __shared__ short As[64 * SLDK];
    __shared__ short Bs[64 * SLDK];

    const int tid = threadIdx.x, lane = tid & 63, wave = tid >> 6;
    const int wm = wave >> 2, wn = wave & 3;
    const int m0 = blockIdx.y * 64, n0 = blockIdx.x * 64;
    const int srow = tid >> 3, scol = (tid & 7) * 16;

    const short* asrc = h_in + (size_t)(m0 + srow) * 1024 + scol;
    const short* bsrc = Whh + (size_t)(n0 + srow) * 1024 + scol;

    uint4 ra0 = *(const uint4*)asrc;
    uint4 ra1 = *(const uint4*)(asrc + 8);
    uint4 rb0 = *(const uint4*)bsrc;
    uint4 rb1 = *(const uint4*)(bsrc + 8);

    f32x4 acc[2];
    acc[0] = (f32x4)0.0f;
    acc[1] = (f32x4)0.0f;

    const int r = lane & 15, q = lane >> 4;
    const int arow = wm * 32 + r, brow = wn * 16 + r;
    const int koff = q * 8;

    for (int chunk = 0; chunk < 8; ++chunk) {
        *(uint4*)&As[srow * SLDK + scol]     = ra0;
        *(uint4*)&As[srow * SLDK + scol + 8] = ra1;
        *(uint4*)&Bs[srow * SLDK + scol]     = rb0;
        *(uint4*)&Bs[srow * SLDK + scol + 8] = rb1;
        __syncthreads();

        if (chunk < 7) {
            int k = (chunk + 1) * 128;
            ra0 = *(const uint4*)(asrc + k);
            ra1 = *(const uint4*)(asrc + k + 8);
            rb0 = *(const uint4*)(bsrc + k);
            rb1 = *(const uint4*)(bsrc + k + 8);
        }

        #pragma unroll
        for (int ks = 0; ks < 4; ++ks) {
            bf16x8 a0 = *(const bf16x8*)&As[arow * SLDK + ks * 32 + koff];
            bf16x8 a1 = *(const bf16x8*)&As[(arow + 16) * SLDK + ks * 32 + koff];
            bf16x8 b  = *(const bf16x8*)&Bs[brow * SLDK + ks * 32 + koff];
            acc[0] = __builtin_amdgcn_mfma_f32_16x16x32_bf16(a0, b, acc[0], 0, 0, 0);
            acc[1] = __builtin_amdgcn_mfma_f32_16x16x32_bf16(a1, b, acc[1], 0, 0, 0);
        }
        __syncthreads();
    }

    const short* zt = Z + ((size_t)t << 20);
    int n = n0 + wn * 16 + r;
    #pragma unroll
    for (int mi = 0; mi < 2; mi++) {
        int mb = m0 + wm * 32 + mi * 16 + q * 4;
        #pragma unroll
        for (int rr = 0; rr < 4; rr++) {
            float z = bf2f(zt[((size_t)(mb + rr) << 10) + n]);
            h_out[((size_t)(mb + rr) << 10) + n] = f2bf(tanh_fast(acc[mi][rr] + z));
        }
    }
}

// ---------- bscan: sync-free batch-split scan ----------
// 64 blocks x 1024 thr. Block owns batch rows m0..m0+15 for ALL 63 steps.
// h-tile lives in LDS the whole scan (zero global h traffic, no grid sync).
// Per step: A (16x1024, XOR-swizzled LDS) x Whh^T (streamed from L2, reg dbuf).
// Wave w owns n-strip [w*64, w*64+64) = 4 x 16-col MFMA frags.
__global__ __launch_bounds__(1024) void bscan(const short* __restrict__ Whh,
                                              const short* __restrict__ Z,
                                              short* __restrict__ hout) {
    __shared__ short Ad[2][16 * 1024];    // 2 x 32 KB h-tile, chunk c at c^(row&7)
    __shared__ short Zs[16 * 1032];       // 33 KB Z tile, +8 shorts row pad

    const int tid = threadIdx.x, lane = tid & 63, wave = tid >> 6;
    const int m0 = blockIdx.x * 16;
    const int r = lane & 15, q = lane >> 4;
    const int nbase = wave * 64;

    // staging coords: thread owns 16B chunks (zc0, zc0+1) of row zrow
    const int zrow = tid >> 6;            // 0..15
    const int zc0 = (tid & 63) * 2;       // 0..126 even

    // Whh row pointers for this lane's B-fragments (row = nbase+nf*16+r, k offset q*8)
    const short* wp0 = Whh + (size_t)(nbase +  0 + r) * 1024 + q * 8;
    const short* wp1 = Whh + (size_t)(nbase + 16 + r) * 1024 + q * 8;
    const short* wp2 = Whh + (size_t)(nbase + 32 + r) * 1024 + q * 8;
    const short* wp3 = Whh + (size_t)(nbase + 48 + r) * 1024 + q * 8;

    // ---- t0: h1 = tanh(Z[0]) -> Ad[0] (swizzled) ----
    {
        const short* z0 = Z + (size_t)(m0 + zrow) * 1024 + zc0 * 8;
        uint4 v0 = tanh8(*(const uint4*)z0);
        uint4 v1 = tanh8(*(const uint4*)(z0 + 8));
        *(uint4*)&Ad[0][zrow * 1024 + ((zc0 ^ (zrow & 7)) << 3)]       = v0;
        *(uint4*)&Ad[0][zrow * 1024 + (((zc0 + 1) ^ (zrow & 7)) << 3)] = v1;
    }
    __syncthreads();

    int cur = 0;
    for (int t = 1; t < 64; ++t) {
        // early Z[t] loads, parked in regs until after the K-loop (T14)
        const short* zt = Z + ((size_t)t << 20) + (size_t)(m0 + zrow) * 1024 + zc0 * 8;
        uint4 zv0 = *(const uint4*)zt;
        uint4 zv1 = *(const uint4*)(zt + 8);

        f32x4 acc[4];
        acc[0] = (f32x4)0.0f; acc[1] = (f32x4)0.0f;
        acc[2] = (f32x4)0.0f; acc[3] = (f32x4)0.0f;

        const short* ab = &Ad[cur][0];

        // B reg double-buffer: b0 = kc, b1 = kc+1 (offsets in shorts: kc*32)
        uint4 b0[4], b1[4];
        b0[0] = *(const uint4*)wp0; b0[1] = *(const uint4*)wp1;
        b0[2] = *(const uint4*)wp2; b0[3] = *(const uint4*)wp3;

        for (int kc = 0; kc < 32; kc += 2) {
            // prefetch kc+1
            b1[0] = *(const uint4*)(wp0 + (kc + 1) * 32);
            b1[1] = *(const uint4*)(wp1 + (kc + 1) * 32);
            b1[2] = *(const uint4*)(wp2 + (kc + 1) * 32);
            b1[3] = *(const uint4*)(wp3 + (kc + 1) * 32);

            bf16x8 a0 = *(const bf16x8*)&ab[r * 1024 + (((kc * 4 + q) ^ (r & 7)) << 3)];
            acc[0] = __builtin_amdgcn_mfma_f32_16x16x32_bf16(a0, *(const bf16x8*)&b0[0], acc[0], 0, 0, 0);
            acc[1] = __builtin_amdgcn_mfma_f32_16x16x32_bf16(a0, *(const bf16x8*)&b0[1], acc[1], 0, 0, 0);
            acc[2] = __builtin_amdgcn_mfma_f32_16x16x32_bf16(a0, *(const bf16x8*)&b0[2], acc[2], 0, 0, 0);
            acc[3] = __builtin_amdgcn_mfma_f32_16x16x32_bf16(a0, *(const bf16x8*)&b0[3], acc[3], 0, 0, 0);

            // prefetch kc+2
            if (kc + 2 < 32) {
                b0[0] = *(const uint4*)(wp0 + (kc + 2) * 32);
                b0[1] = *(const uint4*)(wp1 + (kc + 2) * 32);
                b0[2] = *(const uint4*)(wp2 + (kc + 2) * 32);
                b0[3] = *(const uint4*)(wp3 + (kc + 2) * 32);
            }

            bf16x8 a1 = *(const bf16x8*)&ab[r * 1024 + ((((kc + 1) * 4 + q) ^ (r & 7)) << 3)];
            acc[0] = __builtin_amdgcn_mfma_f32_16x16x32_bf16(a1, *(const bf16x8*)&b1[0], acc[0], 0, 0, 0);
            acc[1] = __builtin_amdgcn_mfma_f32_16x16x32_bf16(a1, *(const bf16x8*)&b1[1], acc[1], 0, 0, 0);
            acc[2] = __builtin_amdgcn_mfma_f32_16x16x32_bf16(a1, *(const bf16x8*)&b1[2], acc[2], 0, 0, 0);
            acc[3] = __builtin_amdgcn_mfma_f32_16x16x32_bf16(a1, *(const bf16x8*)&b1[3], acc[3], 0, 0, 0);
        }

        // park Z into LDS, then epilogue
        *(uint4*)&Zs[zrow * 1032 + zc0 * 8]     = zv0;
        *(uint4*)&Zs[zrow * 1032 + zc0 * 8 + 8] = zv1;
        __syncthreads();   // Zs visible; all Ad[cur] reads complete

        const int nxt = cur ^ 1;
        #pragma unroll
        for (int nf = 0; nf < 4; nf++) {
            int col = nbase + nf * 16 + r;
            int cc = col >> 3, rem = col & 7;
            #pragma unroll
            for (int rr = 0; rr < 4; rr++) {
                int row = q * 4 + rr;
                float z = bf2f(Zs[row * 1032 + col]);
                Ad[nxt][row * 1024 + ((cc ^ (row & 7)) << 3) + rem] =
                    f2bf(tanh_fast(acc[nf][rr] + z));
            }
        }
        __syncthreads();   // Ad[nxt] complete for next step
        cur = nxt;
    }

    // ---- final: h_64 (Ad[cur]) -> hout, un-swizzled coalesced ----
    {
        const short* fin = &Ad[cur][0];
        uint4 v0 = *(const uint4*)&fin[zrow * 1024 + ((zc0 ^ (zrow & 7)) << 3)];
        uint4 v1 = *(const uint4*)&fin[zrow * 1024 + (((zc0 + 1) ^ (zrow & 7)) << 3)];
        short* dst = hout + (size_t)(m0 + zrow) * 1024 + zc0 * 8;
        *(uint4*)dst = v0;
        *(uint4*)(dst + 8) = v1;
    }
}

// ---------- head: p[b] = sigmoid(h . W_out + b_out), wave-per-row ----------
__global__ __launch_bounds__(256) void head_kernel(const short* __restrict__ h,
                                                   const float* __restrict__ W_out,
                                                   const float* __restrict__ b_out,
                                                   float* __restrict__ p) {
    int b    = blockIdx.x * 4 + (threadIdx.x >> 6);
    int lane = threadIdx.x & 63;
    float s = 0.f;
    for (int k = lane; k < 1024; k += 64)
        s += bf2f(h[(size_t)b * 1024 + k]) * W_out[k];
    #pragma unroll
    for (int off = 32; off > 0; off >>= 1) s += __shfl_down(s, off);
    if (lane == 0) p[b] = 1.f / (1.f + __expf(-(s + b_out[0])));
}

// ---------- loss: BCE mean with torch-style log clamp at -100 ----------
__global__ __launch_bounds__(1024) void loss_kernel(const float* __restrict__ p,
                                                    const float* __restrict__ y,
                                                    float* __restrict__ loss) {
    __shared__ float red[1024];
    int b = threadIdx.x;
    float pv = p[b];
    float yb = (y[b] >= 1e-5f) ? 1.f : 0.f;
    float lp = fmaxf(logf(pv), -100.f);
    float l1 = fmaxf(log1pf(-pv), -100.f);
    red[b] = yb * lp + (1.f - yb) * l1;
    __syncthreads();
    for (int s = 512; s > 0; s >>= 1) {
        if (b < s) red[b] += red[b + s];
        __syncthreads();
    }
    if (b == 0) loss[0] = -red[0] / 1024.f;
}

// ---------- launch ----------
extern "C" void kernel_launch(void* const* d_in, const int* in_sizes, int n_in,
                              void* d_out, int out_size, void* d_ws, size_t ws_size,
                              hipStream_t stream) {
    const float* av    = (const float*)d_in[3];
    const float* y     = (const float*)d_in[4];
    const float* W_ih  = (const float*)d_in[5];
    const float* b_ih  = (const float*)d_in[6];
    const float* W_hh  = (const float*)d_in[7];
    const float* b_hh  = (const float*)d_in[8];
    const float* W_out = (const float*)d_in[9];
    const float* b_out = (const float*)d_in[10];
    float* out = (float*)d_out;                      // [0]=loss, [1..1024]=p

    char* ws = (char*)d_ws;
    short* Wih_bf = (short*)ws;                      // 2 MB
    short* Whh_bf = (short*)(ws + (2u << 20));       // 2 MB
    float* bsum   = (float*)(ws + (4u << 20));       // 4 KB
    short* hb0    = (short*)(ws + (5u << 20));       // 2 MB
    short* hb1    = (short*)(ws + (7u << 20));       // 2 MB
    short* Z      = (short*)(ws + (9u << 20));       // 128 MB: [64][1024][1024] bf16
    short* X      = (short*)(ws + (137u << 20));     // 128 MB: bf16 av, scan-row order

    pack_w<<<512, 256, 0, stream>>>(W_ih, Wih_bf);
    pack_w<<<512, 256, 0, stream>>>(W_hh, Whh_bf);
    prep_b<<<1, 1024, 0, stream>>>(b_ih, b_hh, bsum);

    bool bigws = ws_size >= ((size_t)266 << 20);

    if (bigws) {
        conv_av<<<32768, 256, 0, stream>>>(av, X);
        zgemm2<<<dim3(8, 512), 256, 0, stream>>>(X, Wih_bf, bsum, Z);
        bscan<<<64, 1024, 0, stream>>>(Whh_bf, Z, hb0);
    } else {
        zgemm<<<dim3(8, 512), 256, 0, stream>>>(av, Wih_bf, bsum, Z);
        short* hbuf[2] = { hb0, hb1 };
        t0_kernel<<<512, 256, 0, stream>>>(Z, hb1);
        for (int t = 1; t < 64; ++t)
            step_kernel<<<dim3(16, 16), 512, 0, stream>>>(Whh_bf, Z, hbuf[t & 1], hbuf[(t + 1) & 1], t);
    }
    // both paths: final h in hb0

    head_kernel<<<256, 256, 0, stream>>>(hb0, W_out, b_out, out + 1);
    loss_kernel<<<1, 1024, 0, stream>>>(out + 1, y, out);
}

// Round 6
// 1451.811 us; speedup vs baseline: 2.8477x; 2.8477x over previous
//
#include <hip/hip_runtime.h>

// ---------- types ----------
typedef __attribute__((ext_vector_type(8))) short bf16x8;   // 8 bf16 in 4 VGPRs
typedef __attribute__((ext_vector_type(4))) float f32x4;

// ---------- bf16 helpers (RNE, bit-level) ----------
__device__ __forceinline__ short f2bf(float f) {
    union { float f; unsigned u; } v; v.f = f;
    unsigned r = v.u + 0x7fffu + ((v.u >> 16) & 1u);
    return (short)(r >> 16);
}
__device__ __forceinline__ float bf2f(short s) {
    union { unsigned u; float f; } v; v.u = ((unsigned)(unsigned short)s) << 16;
    return v.f;
}
__device__ __forceinline__ unsigned pack2(float x, float y) {
    return (unsigned)(unsigned short)f2bf(x) | ((unsigned)(unsigned short)f2bf(y) << 16);
}
__device__ __forceinline__ uint4 pack8(float4 a, float4 b) {
    return make_uint4(pack2(a.x, a.y), pack2(a.z, a.w), pack2(b.x, b.y), pack2(b.z, b.w));
}
__device__ __forceinline__ float tanh_fast(float x) {
    float e = __expf(2.f * x);
    return 1.f - 2.f / (e + 1.f);
}
__device__ __forceinline__ uint4 tanh8(uint4 zv) {
    const unsigned* zp = (const unsigned*)&zv;
    uint4 out;
    unsigned* op = (unsigned*)&out;
    #pragma unroll
    for (int j = 0; j < 4; j++) {
        float lo = tanh_fast(bf2f((short)(zp[j] & 0xffffu)));
        float hi = tanh_fast(bf2f((short)(zp[j] >> 16)));
        op[j] = pack2(lo, hi);
    }
    return out;
}

// async global -> LDS, 16B per lane (dest = wave-uniform base + lane*16)
__device__ __forceinline__ void gll16(const void* gp, void* lp) {
    __builtin_amdgcn_global_load_lds(
        (__attribute__((address_space(1))) void*)gp,
        (__attribute__((address_space(3))) void*)lp, 16, 0, 0);
}

// ---------- prep: fp32 [1024][1024] -> bf16 ----------
__global__ __launch_bounds__(256) void pack_w(const float* __restrict__ src,
                                              short* __restrict__ dst) {
    int idx = (blockIdx.x * 256 + threadIdx.x) * 8;
    float4 f0 = ((const float4*)(src + idx))[0];
    float4 f1 = ((const float4*)(src + idx))[1];
    *(uint4*)(dst + idx) = pack8(f0, f1);
}

__global__ void prep_b(const float* __restrict__ b_ih, const float* __restrict__ b_hh,
                       float* __restrict__ bsum) {
    int n = threadIdx.x;
    bsum[n] = b_ih[n] + b_hh[n];
}

// ---------- convert av fp32 [b][t][k] -> bf16 X[t*1024+b][k] (scan-row order) ----------
__global__ __launch_bounds__(256) void conv_av(const float* __restrict__ av,
                                               short* __restrict__ X) {
    size_t e = ((size_t)blockIdx.x * 256 + threadIdx.x) * 8;
    size_t row = e >> 10;                 // b*64 + t
    int k = (int)(e & 1023);
    int b = (int)(row >> 6), t = (int)(row & 63);
    float4 f0 = *(const float4*)(av + e);
    float4 f1 = *(const float4*)(av + e + 4);
    *(uint4*)(X + ((size_t)t * 1024 + b) * 1024 + k) = pack8(f0, f1);
}

// ---------- zgemm2: m97-structure bf16 GEMM, XOR swizzle + XCD-chunked block map ----------
// Z[r][n] = X[r][k] . Wih[n][k] + bsum[n];  M=65536, N=1024, K=1024
// 1D grid 4096; pid -> (mt,nt) so each XCD owns a contiguous 64-mt band (T1, bijective).
__global__ __launch_bounds__(256) void zgemm2(const short* __restrict__ X,
                                              const short* __restrict__ Wih,
                                              const float* __restrict__ bsum,
                                              short* __restrict__ Z) {
    __shared__ short smem[16384];         // 32KB: As[128][64] + Bs[128][64]; epilogue: C[128][128]
    short* As = smem;
    short* Bs = smem + 8192;

    const int tid = threadIdx.x, lane = tid & 63, wave = tid >> 6;
    const int wm = wave >> 1, wn = wave & 1;
    const int pid = blockIdx.x;
    const int slot = pid >> 3;
    const int mt = (pid & 7) * 64 + (slot >> 3);  // 0..511
    const int nt = slot & 7;                      // 0..7
    const int m0 = mt * 128, n0 = nt * 128;

    const int srow = wave * 32 + (lane >> 3);
    const int scol = ((lane & 7) ^ (lane >> 3)) * 8;
    const short* asrc = X   + (size_t)(m0 + srow) * 1024 + scol;
    const short* bsrc = Wih + (size_t)(n0 + srow) * 1024 + scol;
    char* aldst = (char*)As + wave * 4096;
    char* bldst = (char*)Bs + wave * 4096;

    f32x4 acc[4][4];
    #pragma unroll
    for (int i = 0; i < 4; i++)
        #pragma unroll
        for (int j = 0; j < 4; j++) acc[i][j] = (f32x4)0.0f;

    const int r = lane & 15, q = lane >> 4;

    for (int kt = 0; kt < 16; ++kt) {
        const int kbase = kt * 64;
        #pragma unroll
        for (int i = 0; i < 4; i++) {
            gll16(asrc + kbase + i * 8192, aldst + i * 1024);
            gll16(bsrc + kbase + i * 8192, bldst + i * 1024);
        }
        __syncthreads();

        #pragma unroll
        for (int ks = 0; ks < 2; ++ks) {
            bf16x8 af[4], bfr[4];
            #pragma unroll
            for (int i = 0; i < 4; i++) {
                int ar = wm * 64 + i * 16 + r;
                int br = wn * 64 + i * 16 + r;
                af[i]  = *(const bf16x8*)&As[ar * 64 + (((ks * 4 + q) ^ (r & 7)) << 3)];
                bfr[i] = *(const bf16x8*)&Bs[br * 64 + (((ks * 4 + q) ^ (r & 7)) << 3)];
            }
            #pragma unroll
            for (int i = 0; i < 4; i++)
                #pragma unroll
                for (int j = 0; j < 4; j++)
                    acc[i][j] = __builtin_amdgcn_mfma_f32_16x16x32_bf16(af[i], bfr[j], acc[i][j], 0, 0, 0);
        }
        __syncthreads();
    }

    short* Csh = smem;    // [128][128] shorts = 32KB
    #pragma unroll
    for (int j = 0; j < 4; j++) {
        int colc = wn * 64 + j * 16 + r;
        float bs = bsum[n0 + colc];
        int chunkc = colc >> 3, rem = colc & 7;
        #pragma unroll
        for (int i = 0; i < 4; i++) {
            int rowb = wm * 64 + i * 16 + q * 4;
            #pragma unroll
            for (int rr = 0; rr < 4; rr++) {
                int row = rowb + rr;
                int sc = ((chunkc ^ (row & 7)) << 3) | rem;
                Csh[row * 128 + sc] = f2bf(acc[i][j][rr] + bs);
            }
        }
    }
    __syncthreads();
    #pragma unroll
    for (int p = 0; p < 8; p++) {
        int row = p * 16 + (tid >> 4);
        int chunk = tid & 15;
        int rc = chunk ^ (row & 7);
        uint4 v = *(const uint4*)&Csh[row * 128 + rc * 8];
        *(uint4*)(Z + (size_t)(m0 + row) * 1024 + n0 + chunk * 8) = v;
    }
}

// ---------- fallback zgemm (used only if ws too small for X) ----------
#define ZLDK 72

__global__ __launch_bounds__(256) void zgemm(const float* __restrict__ av,
                                             const short* __restrict__ Wih,
                                             const float* __restrict__ bsum,
                                             short* __restrict__ Z) {
    __shared__ short As[128 * ZLDK];
    __shared__ short Bs[128 * ZLDK];

    const int tid = threadIdx.x, lane = tid & 63, wave = tid >> 6;
    const int wm = wave >> 1, wn = wave & 1;
    const int m0 = blockIdx.y * 128, n0 = blockIdx.x * 128;
    const int srow = tid >> 1, scol = (tid & 1) * 32;

    const int gr = m0 + srow;
    const int tt = gr >> 10, bb = gr & 1023;
    const float* asrc = av + ((size_t)bb * 64 + tt) * 1024 + scol;
    const short* bsrc = Wih + (size_t)(n0 + srow) * 1024 + scol;

    uint4 ra[4], rb[4];
    #pragma unroll
    for (int j = 0; j < 4; j++) {
        float4 f0 = *(const float4*)(asrc + 8 * j);
        float4 f1 = *(const float4*)(asrc + 8 * j + 4);
        ra[j] = pack8(f0, f1);
        rb[j] = *(const uint4*)(bsrc + 8 * j);
    }

    f32x4 acc[4][4];
    #pragma unroll
    for (int i = 0; i < 4; i++)
        #pragma unroll
        for (int j = 0; j < 4; j++) acc[i][j] = (f32x4)0.0f;

    const int r = lane & 15, q = lane >> 4;
    const int koff = q * 8;

    for (int kt = 0; kt < 16; ++kt) {
        #pragma unroll
        for (int j = 0; j < 4; j++) {
            *(uint4*)&As[srow * ZLDK + scol + 8 * j] = ra[j];
            *(uint4*)&Bs[srow * ZLDK + scol + 8 * j] = rb[j];
        }
        __syncthreads();

        if (kt < 15) {
            int k = (kt + 1) * 64;
            #pragma unroll
            for (int j = 0; j < 4; j++) {
                float4 f0 = *(const float4*)(asrc + k + 8 * j);
                float4 f1 = *(const float4*)(asrc + k + 8 * j + 4);
                ra[j] = pack8(f0, f1);
                rb[j] = *(const uint4*)(bsrc + k + 8 * j);
            }
        }

        #pragma unroll
        for (int ks = 0; ks < 2; ++ks) {
            bf16x8 af[4], bfr[4];
            #pragma unroll
            for (int i = 0; i < 4; i++) {
                af[i]  = *(const bf16x8*)&As[(wm * 64 + i * 16 + r) * ZLDK + ks * 32 + koff];
                bfr[i] = *(const bf16x8*)&Bs[(wn * 64 + i * 16 + r) * ZLDK + ks * 32 + koff];
            }
            #pragma unroll
            for (int i = 0; i < 4; i++)
                #pragma unroll
                for (int j = 0; j < 4; j++)
                    acc[i][j] = __builtin_amdgcn_mfma_f32_16x16x32_bf16(af[i], bfr[j], acc[i][j], 0, 0, 0);
        }
        __syncthreads();
    }

    #pragma unroll
    for (int j = 0; j < 4; j++) {
        int n = n0 + wn * 64 + j * 16 + r;
        float bs = bsum[n];
        #pragma unroll
        for (int i = 0; i < 4; i++) {
            int mb = m0 + wm * 64 + i * 16 + q * 4;
            #pragma unroll
            for (int rr = 0; rr < 4; rr++)
                Z[(size_t)(mb + rr) * 1024 + n] = f2bf(acc[i][j][rr] + bs);
        }
    }
}

// ---------- t=0: h1 = tanh(Z[0]) elementwise ----------
__global__ __launch_bounds__(256) void t0_kernel(const short* __restrict__ Z,
                                                 short* __restrict__ h) {
    int idx = (blockIdx.x * 256 + threadIdx.x) * 8;
    *(uint4*)(h + idx) = tanh8(*(const uint4*)(Z + idx));
}

// ---------- step2: one RNN step, full-chip lockstep (launch boundary = global barrier) ----------
// h'[m][n] = tanh(h[m][k] . Whh[n][k] + Z[t][m][n]);  M=N=K=1024
// grid (8,32): n0 = bx*128, m0 = by*32.  512 thr, 8 waves; wave w owns n-cols [w*16,+16).
// LDS: As[32][1024] (64KB, h-strip, chunk-XOR swizzled via pre-swizzled gll16 source),
//      Zs[32][128] (8KB, linear), Csh[32][128] (8KB, swizzled store->coalesced write).
// One barrier after staging, one before the coalesced output. 80KB -> 2 blocks/CU.
__global__ __launch_bounds__(512) void step2(const short* __restrict__ Whh,
                                             const short* __restrict__ Z,
                                             const short* __restrict__ h_in,
                                             short* __restrict__ h_out, int t) {
    __shared__ short As[32 * 1024];
    __shared__ short Zs[32 * 128];
    __shared__ short Csh[32 * 128];

    const int tid = threadIdx.x, lane = tid & 63, wave = tid >> 6;
    const int m0 = blockIdx.y * 32, n0 = blockIdx.x * 128;
    const int r = lane & 15, q = lane >> 4;

    // ---- stage h-strip: 64 gll16 (8/wave), LDS slot (R,c) holds global chunk c^(R&7) ----
    #pragma unroll
    for (int i = 0; i < 8; i++) {
        int j = wave * 8 + i;             // 0..63: half-row j
        int R = j >> 1, half = j & 1;
        const short* src = h_in + (size_t)(m0 + R) * 1024 + half * 512
                         + ((lane ^ (R & 7)) << 3);
        gll16(src, (char*)As + j * 1024);
    }
    // ---- stage Z tile: 8 gll16 (1/wave), linear [32][128] ----
    {
        const short* src = Z + ((size_t)t << 20)
                         + (size_t)(m0 + wave * 4 + (lane >> 4)) * 1024
                         + n0 + ((lane & 15) << 3);
        gll16(src, (char*)Zs + wave * 1024);
    }
    __syncthreads();                      // vmcnt(0) drained by compiler before barrier

    // ---- K-loop: A from LDS (conflict-free), B streamed from L2-hot Whh ----
    const short* wp = Whh + (size_t)(n0 + wave * 16 + r) * 1024 + q * 8;
    const int axor = r & 7;
    f32x4 acc0 = (f32x4)0.0f, acc1 = (f32x4)0.0f;

    #pragma unroll 8
    for (int ks = 0; ks < 32; ++ks) {
        int co = ((ks * 4 + q) ^ axor) << 3;
        bf16x8 a0 = *(const bf16x8*)&As[r * 1024 + co];
        bf16x8 a1 = *(const bf16x8*)&As[(16 + r) * 1024 + co];
        bf16x8 b  = *(const bf16x8*)(wp + ks * 32);
        acc0 = __builtin_amdgcn_mfma_f32_16x16x32_bf16(a0, b, acc0, 0, 0, 0);
        acc1 = __builtin_amdgcn_mfma_f32_16x16x32_bf16(a1, b, acc1, 0, 0, 0);
    }

    // ---- epilogue: +Z, tanh -> Csh (swizzled), then coalesced 16B stores ----
    const int col = wave * 16 + r;
    const int cc = col >> 3, rem = col & 7;
    #pragma unroll
    for (int mi = 0; mi < 2; mi++) {
        const f32x4 a = mi ? acc1 : acc0;
        #pragma unroll
        for (int rr = 0; rr < 4; rr++) {
            int row = mi * 16 + q * 4 + rr;
            float z = bf2f(Zs[row * 128 + col]);
            Csh[row * 128 + ((cc ^ (row & 7)) << 3) + rem] = f2bf(tanh_fast(a[rr] + z));
        }
    }
    __syncthreads();
    {
        int row = tid >> 4, chunk = tid & 15;
        int rc = chunk ^ (row & 7);
        uint4 v = *(const uint4*)&Csh[row * 128 + rc * 8];
        *(uint4*)(h_out + (size_t)(m0 + row) * 1024 + n0 + chunk * 8) = v;
    }
}

// ---------- head: p[b] = sigmoid(h . W_out + b_out), wave-per-row ----------
__global__ __launch_bounds__(256) void head_kernel(const short* __restrict__ h,
                                                   const float* __restrict__ W_out,
                                                   const float* __restrict__ b_out,
                                                   float* __restrict__ p) {
    int b    = blockIdx.x * 4 + (threadIdx.x >> 6);
    int lane = threadIdx.x & 63;
    float s = 0.f;
    for (int k = lane; k < 1024; k += 64)
        s += bf2f(h[(size_t)b * 1024 + k]) * W_out[k];
    #pragma unroll
    for (int off = 32; off > 0; off >>= 1) s += __shfl_down(s, off);
    if (lane == 0) p[b] = 1.f / (1.f + __expf(-(s + b_out[0])));
}

// ---------- loss: BCE mean with torch-style log clamp at -100 ----------
__global__ __launch_bounds__(1024) void loss_kernel(const float* __restrict__ p,
                                                    const float* __restrict__ y,
                                                    float* __restrict__ loss) {
    __shared__ float red[1024];
    int b = threadIdx.x;
    float pv = p[b];
    float yb = (y[b] >= 1e-5f) ? 1.f : 0.f;
    float lp = fmaxf(logf(pv), -100.f);
    float l1 = fmaxf(log1pf(-pv), -100.f);
    red[b] = yb * lp + (1.f - yb) * l1;
    __syncthreads();
    for (int s = 512; s > 0; s >>= 1) {
        if (b < s) red[b] += red[b + s];
        __syncthreads();
    }
    if (b == 0) loss[0] = -red[0] / 1024.f;
}

// ---------- launch ----------
extern "C" void kernel_launch(void* const* d_in, const int* in_sizes, int n_in,
                              void* d_out, int out_size, void* d_ws, size_t ws_size,
                              hipStream_t stream) {
    const float* av    = (const float*)d_in[3];
    const float* y     = (const float*)d_in[4];
    const float* W_ih  = (const float*)d_in[5];
    const float* b_ih  = (const float*)d_in[6];
    const float* W_hh  = (const float*)d_in[7];
    const float* b_hh  = (const float*)d_in[8];
    const float* W_out = (const float*)d_in[9];
    const float* b_out = (const float*)d_in[10];
    float* out = (float*)d_out;                      // [0]=loss, [1..1024]=p

    char* ws = (char*)d_ws;
    short* Wih_bf = (short*)ws;                      // 2 MB
    short* Whh_bf = (short*)(ws + (2u << 20));       // 2 MB
    float* bsum   = (float*)(ws + (4u << 20));       // 4 KB
    short* hb0    = (short*)(ws + (5u << 20));       // 2 MB
    short* hb1    = (short*)(ws + (7u << 20));       // 2 MB
    short* Z      = (short*)(ws + (9u << 20));       // 128 MB: [64][1024][1024] bf16
    short* X      = (short*)(ws + (137u << 20));     // 128 MB: bf16 av, scan-row order

    pack_w<<<512, 256, 0, stream>>>(W_ih, Wih_bf);
    pack_w<<<512, 256, 0, stream>>>(W_hh, Whh_bf);
    prep_b<<<1, 1024, 0, stream>>>(b_ih, b_hh, bsum);

    bool bigws = ws_size >= ((size_t)266 << 20);

    if (bigws) {
        conv_av<<<32768, 256, 0, stream>>>(av, X);
        zgemm2<<<4096, 256, 0, stream>>>(X, Wih_bf, bsum, Z);
    } else {
        zgemm<<<dim3(8, 512), 256, 0, stream>>>(av, Wih_bf, bsum, Z);
    }

    short* hbuf[2] = { hb0, hb1 };
    t0_kernel<<<512, 256, 0, stream>>>(Z, hb1);      // h_1 = tanh(Z[0])
    for (int t = 1; t < 64; ++t)
        step2<<<dim3(8, 32), 512, 0, stream>>>(Whh_bf, Z, hbuf[t & 1], hbuf[(t + 1) & 1], t);
    // t=63 writes hb0

    head_kernel<<<256, 256, 0, stream>>>(hb0, W_out, b_out, out + 1);
    loss_kernel<<<1, 1024, 0, stream>>>(out + 1, y, out);
}

// Round 7
// 1255.289 us; speedup vs baseline: 3.2935x; 1.1566x over previous
//
#include <hip/hip_runtime.h>

// ---------- types ----------
typedef __attribute__((ext_vector_type(8))) short bf16x8;   // 8 bf16 in 4 VGPRs
typedef __attribute__((ext_vector_type(4))) float f32x4;

// ---------- bf16 helpers (RNE, bit-level) ----------
__device__ __forceinline__ short f2bf(float f) {
    union { float f; unsigned u; } v; v.f = f;
    unsigned r = v.u + 0x7fffu + ((v.u >> 16) & 1u);
    return (short)(r >> 16);
}
__device__ __forceinline__ float bf2f(short s) {
    union { unsigned u; float f; } v; v.u = ((unsigned)(unsigned short)s) << 16;
    return v.f;
}
__device__ __forceinline__ unsigned pack2(float x, float y) {
    return (unsigned)(unsigned short)f2bf(x) | ((unsigned)(unsigned short)f2bf(y) << 16);
}
__device__ __forceinline__ uint4 pack8(float4 a, float4 b) {
    return make_uint4(pack2(a.x, a.y), pack2(a.z, a.w), pack2(b.x, b.y), pack2(b.z, b.w));
}
__device__ __forceinline__ float tanh_fast(float x) {
    float e = __expf(2.f * x);
    return 1.f - 2.f / (e + 1.f);
}
__device__ __forceinline__ uint4 tanh8(uint4 zv) {
    const unsigned* zp = (const unsigned*)&zv;
    uint4 out;
    unsigned* op = (unsigned*)&out;
    #pragma unroll
    for (int j = 0; j < 4; j++) {
        float lo = tanh_fast(bf2f((short)(zp[j] & 0xffffu)));
        float hi = tanh_fast(bf2f((short)(zp[j] >> 16)));
        op[j] = pack2(lo, hi);
    }
    return out;
}

// async global -> LDS, 16B per lane (dest = wave-uniform base + lane*16)
__device__ __forceinline__ void gll16(const void* gp, void* lp) {
    __builtin_amdgcn_global_load_lds(
        (__attribute__((address_space(1))) void*)gp,
        (__attribute__((address_space(3))) void*)lp, 16, 0, 0);
}

// ---------- prep: fp32 [1024][1024] -> bf16 ----------
__global__ __launch_bounds__(256) void pack_w(const float* __restrict__ src,
                                              short* __restrict__ dst) {
    int idx = (blockIdx.x * 256 + threadIdx.x) * 8;
    float4 f0 = ((const float4*)(src + idx))[0];
    float4 f1 = ((const float4*)(src + idx))[1];
    *(uint4*)(dst + idx) = pack8(f0, f1);
}

__global__ void prep_b(const float* __restrict__ b_ih, const float* __restrict__ b_hh,
                       float* __restrict__ bsum) {
    int n = threadIdx.x;
    bsum[n] = b_ih[n] + b_hh[n];
}

// ---------- convert av fp32 [b][t][k] -> bf16 X[t*1024+b][k] (scan-row order) ----------
__global__ __launch_bounds__(256) void conv_av(const float* __restrict__ av,
                                               short* __restrict__ X) {
    size_t e = ((size_t)blockIdx.x * 256 + threadIdx.x) * 8;
    size_t row = e >> 10;                 // b*64 + t
    int k = (int)(e & 1023);
    int b = (int)(row >> 6), t = (int)(row & 63);
    float4 f0 = *(const float4*)(av + e);
    float4 f1 = *(const float4*)(av + e + 4);
    *(uint4*)(X + ((size_t)t * 1024 + b) * 1024 + k) = pack8(f0, f1);
}

// ---------- zgemm2: m97-structure bf16 GEMM, XOR swizzle + XCD-chunked map (R6-verified) ----------
__global__ __launch_bounds__(256) void zgemm2(const short* __restrict__ X,
                                              const short* __restrict__ Wih,
                                              const float* __restrict__ bsum,
                                              short* __restrict__ Z) {
    __shared__ short smem[16384];         // 32KB: As[128][64] + Bs[128][64]; epilogue: C[128][128]
    short* As = smem;
    short* Bs = smem + 8192;

    const int tid = threadIdx.x, lane = tid & 63, wave = tid >> 6;
    const int wm = wave >> 1, wn = wave & 1;
    const int pid = blockIdx.x;
    const int slot = pid >> 3;
    const int mt = (pid & 7) * 64 + (slot >> 3);  // 0..511
    const int nt = slot & 7;                      // 0..7
    const int m0 = mt * 128, n0 = nt * 128;

    const int srow = wave * 32 + (lane >> 3);
    const int scol = ((lane & 7) ^ (lane >> 3)) * 8;
    const short* asrc = X   + (size_t)(m0 + srow) * 1024 + scol;
    const short* bsrc = Wih + (size_t)(n0 + srow) * 1024 + scol;
    char* aldst = (char*)As + wave * 4096;
    char* bldst = (char*)Bs + wave * 4096;

    f32x4 acc[4][4];
    #pragma unroll
    for (int i = 0; i < 4; i++)
        #pragma unroll
        for (int j = 0; j < 4; j++) acc[i][j] = (f32x4)0.0f;

    const int r = lane & 15, q = lane >> 4;

    for (int kt = 0; kt < 16; ++kt) {
        const int kbase = kt * 64;
        #pragma unroll
        for (int i = 0; i < 4; i++) {
            gll16(asrc + kbase + i * 8192, aldst + i * 1024);
            gll16(bsrc + kbase + i * 8192, bldst + i * 1024);
        }
        __syncthreads();

        #pragma unroll
        for (int ks = 0; ks < 2; ++ks) {
            bf16x8 af[4], bfr[4];
            #pragma unroll
            for (int i = 0; i < 4; i++) {
                int ar = wm * 64 + i * 16 + r;
                int br = wn * 64 + i * 16 + r;
                af[i]  = *(const bf16x8*)&As[ar * 64 + (((ks * 4 + q) ^ (r & 7)) << 3)];
                bfr[i] = *(const bf16x8*)&Bs[br * 64 + (((ks * 4 + q) ^ (r & 7)) << 3)];
            }
            #pragma unroll
            for (int i = 0; i < 4; i++)
                #pragma unroll
                for (int j = 0; j < 4; j++)
                    acc[i][j] = __builtin_amdgcn_mfma_f32_16x16x32_bf16(af[i], bfr[j], acc[i][j], 0, 0, 0);
        }
        __syncthreads();
    }

    short* Csh = smem;    // [128][128] shorts = 32KB
    #pragma unroll
    for (int j = 0; j < 4; j++) {
        int colc = wn * 64 + j * 16 + r;
        float bs = bsum[n0 + colc];
        int chunkc = colc >> 3, rem = colc & 7;
        #pragma unroll
        for (int i = 0; i < 4; i++) {
            int rowb = wm * 64 + i * 16 + q * 4;
            #pragma unroll
            for (int rr = 0; rr < 4; rr++) {
                int row = rowb + rr;
                int sc = ((chunkc ^ (row & 7)) << 3) | rem;
                Csh[row * 128 + sc] = f2bf(acc[i][j][rr] + bs);
            }
        }
    }
    __syncthreads();
    #pragma unroll
    for (int p = 0; p < 8; p++) {
        int row = p * 16 + (tid >> 4);
        int chunk = tid & 15;
        int rc = chunk ^ (row & 7);
        uint4 v = *(const uint4*)&Csh[row * 128 + rc * 8];
        *(uint4*)(Z + (size_t)(m0 + row) * 1024 + n0 + chunk * 8) = v;
    }
}

// ---------- fallback zgemm (used only if ws too small for X) ----------
#define ZLDK 72

__global__ __launch_bounds__(256) void zgemm(const float* __restrict__ av,
                                             const short* __restrict__ Wih,
                                             const float* __restrict__ bsum,
                                             short* __restrict__ Z) {
    __shared__ short As[128 * ZLDK];
    __shared__ short Bs[128 * ZLDK];

    const int tid = threadIdx.x, lane = tid & 63, wave = tid >> 6;
    const int wm = wave >> 1, wn = wave & 1;
    const int m0 = blockIdx.y * 128, n0 = blockIdx.x * 128;
    const int srow = tid >> 1, scol = (tid & 1) * 32;

    const int gr = m0 + srow;
    const int tt = gr >> 10, bb = gr & 1023;
    const float* asrc = av + ((size_t)bb * 64 + tt) * 1024 + scol;
    const short* bsrc = Wih + (size_t)(n0 + srow) * 1024 + scol;

    uint4 ra[4], rb[4];
    #pragma unroll
    for (int j = 0; j < 4; j++) {
        float4 f0 = *(const float4*)(asrc + 8 * j);
        float4 f1 = *(const float4*)(asrc + 8 * j + 4);
        ra[j] = pack8(f0, f1);
        rb[j] = *(const uint4*)(bsrc + 8 * j);
    }

    f32x4 acc[4][4];
    #pragma unroll
    for (int i = 0; i < 4; i++)
        #pragma unroll
        for (int j = 0; j < 4; j++) acc[i][j] = (f32x4)0.0f;

    const int r = lane & 15, q = lane >> 4;
    const int koff = q * 8;

    for (int kt = 0; kt < 16; ++kt) {
        #pragma unroll
        for (int j = 0; j < 4; j++) {
            *(uint4*)&As[srow * ZLDK + scol + 8 * j] = ra[j];
            *(uint4*)&Bs[srow * ZLDK + scol + 8 * j] = rb[j];
        }
        __syncthreads();

        if (kt < 15) {
            int k = (kt + 1) * 64;
            #pragma unroll
            for (int j = 0; j < 4; j++) {
                float4 f0 = *(const float4*)(asrc + k + 8 * j);
                float4 f1 = *(const float4*)(asrc + k + 8 * j + 4);
                ra[j] = pack8(f0, f1);
                rb[j] = *(const uint4*)(bsrc + k + 8 * j);
            }
        }

        #pragma unroll
        for (int ks = 0; ks < 2; ++ks) {
            bf16x8 af[4], bfr[4];
            #pragma unroll
            for (int i = 0; i < 4; i++) {
                af[i]  = *(const bf16x8*)&As[(wm * 64 + i * 16 + r) * ZLDK + ks * 32 + koff];
                bfr[i] = *(const bf16x8*)&Bs[(wn * 64 + i * 16 + r) * ZLDK + ks * 32 + koff];
            }
            #pragma unroll
            for (int i = 0; i < 4; i++)
                #pragma unroll
                for (int j = 0; j < 4; j++)
                    acc[i][j] = __builtin_amdgcn_mfma_f32_16x16x32_bf16(af[i], bfr[j], acc[i][j], 0, 0, 0);
        }
        __syncthreads();
    }

    #pragma unroll
    for (int j = 0; j < 4; j++) {
        int n = n0 + wn * 64 + j * 16 + r;
        float bs = bsum[n];
        #pragma unroll
        for (int i = 0; i < 4; i++) {
            int mb = m0 + wm * 64 + i * 16 + q * 4;
            #pragma unroll
            for (int rr = 0; rr < 4; rr++)
                Z[(size_t)(mb + rr) * 1024 + n] = f2bf(acc[i][j][rr] + bs);
        }
    }
}

// ---------- t=0: h1 = tanh(Z[0]) elementwise ----------
__global__ __launch_bounds__(256) void t0_kernel(const short* __restrict__ Z,
                                                 short* __restrict__ h) {
    int idx = (blockIdx.x * 256 + threadIdx.x) * 8;
    *(uint4*)(h + idx) = tanh8(*(const uint4*)(Z + idx));
}

// ---------- RNN step (fallback path) ----------
#define SLDK 136

__global__ __launch_bounds__(512) void step_kernel(const short* __restrict__ Whh,
                                                   const short* __restrict__ Z,
                                                   const short* __restrict__ h_in,
                                                   short* __restrict__ h_out, int t) {
    __shared__ short As[64 * SLDK];
    __shared__ short Bs[64 * SLDK];

    const int tid = threadIdx.x, lane = tid & 63, wave = tid >> 6;
    const int wm = wave >> 2, wn = wave & 3;
    const int m0 = blockIdx.y * 64, n0 = blockIdx.x * 64;
    const int srow = tid >> 3, scol = (tid & 7) * 16;

    const short* asrc = h_in + (size_t)(m0 + srow) * 1024 + scol;
    const short* bsrc = Whh + (size_t)(n0 + srow) * 1024 + scol;

    uint4 ra0 = *(const uint4*)asrc;
    uint4 ra1 = *(const uint4*)(asrc + 8);
    uint4 rb0 = *(const uint4*)bsrc;
    uint4 rb1 = *(const uint4*)(bsrc + 8);

    f32x4 acc[2];
    acc[0] = (f32x4)0.0f;
    acc[1] = (f32x4)0.0f;

    const int r = lane & 15, q = lane >> 4;
    const int arow = wm * 32 + r, brow = wn * 16 + r;
    const int koff = q * 8;

    for (int chunk = 0; chunk < 8; ++chunk) {
        *(uint4*)&As[srow * SLDK + scol]     = ra0;
        *(uint4*)&As[srow * SLDK + scol + 8] = ra1;
        *(uint4*)&Bs[srow * SLDK + scol]     = rb0;
        *(uint4*)&Bs[srow * SLDK + scol + 8] = rb1;
        __syncthreads();

        if (chunk < 7) {
            int k = (chunk + 1) * 128;
            ra0 = *(const uint4*)(asrc + k);
            ra1 = *(const uint4*)(asrc + k + 8);
            rb0 = *(const uint4*)(bsrc + k);
            rb1 = *(const uint4*)(bsrc + k + 8);
        }

        #pragma unroll
        for (int ks = 0; ks < 4; ++ks) {
            bf16x8 a0 = *(const bf16x8*)&As[arow * SLDK + ks * 32 + koff];
            bf16x8 a1 = *(const bf16x8*)&As[(arow + 16) * SLDK + ks * 32 + koff];
            bf16x8 b  = *(const bf16x8*)&Bs[brow * SLDK + ks * 32 + koff];
            acc[0] = __builtin_amdgcn_mfma_f32_16x16x32_bf16(a0, b, acc[0], 0, 0, 0);
            acc[1] = __builtin_amdgcn_mfma_f32_16x16x32_bf16(a1, b, acc[1], 0, 0, 0);
        }
        __syncthreads();
    }

    const short* zt = Z + ((size_t)t << 20);
    int n = n0 + wn * 16 + r;
    #pragma unroll
    for (int mi = 0; mi < 2; mi++) {
        int mb = m0 + wm * 32 + mi * 16 + q * 4;
        #pragma unroll
        for (int rr = 0; rr < 4; rr++) {
            float z = bf2f(zt[((size_t)(mb + rr) << 10) + n]);
            h_out[((size_t)(mb + rr) << 10) + n] = f2bf(tanh_fast(acc[mi][rr] + z));
        }
    }
}

// ---------- step3: one RNN step, m97-style pipeline ----------
// h' = tanh(h . Whh^T + Z[t]);  64x64 tile, grid 256 (XCD-bijective), 512 thr 8 waves (2x4).
// BK=128 dbuf via global_load_lds (pre-swizzled src, 0-conflict ds_read), 1 barrier/chunk.
// Z tile gll16'd to LDS; epilogue via swizzled LDS C-tile -> coalesced 16B stores.
// LDS: As 2x16KB + Bs 2x16KB + Zs 8KB = 72 KB.
__global__ __launch_bounds__(512) void step3(const short* __restrict__ Whh,
                                             const short* __restrict__ Z,
                                             const short* __restrict__ h_in,
                                             short* __restrict__ h_out, int t) {
    __shared__ short As[2][64 * 128];
    __shared__ short Bs[2][64 * 128];
    __shared__ short Zs[64 * 64];

    const int tid = threadIdx.x, lane = tid & 63, wave = tid >> 6;
    const int wm = wave >> 2, wn = wave & 3;          // 2 x 4 waves
    const int pid = blockIdx.x;
    // XCD-bijective map: XCD x owns n-tiles {2x, 2x+1} -> Whh slice L2-local
    const int bx = ((pid & 7) << 1) | ((pid >> 3) & 1);   // 0..15 n-tile
    const int by = pid >> 4;                              // 0..15 m-tile
    const int m0 = by * 64, n0 = bx * 64;
    const int r = lane & 15, q = lane >> 4;

    // staging geometry: per gll16 round a wave covers 4 rows x 256B;
    // LDS slot (R, c) holds global 16B-chunk c ^ (R&7)
    const int c16 = lane & 15;
    const int R0 = wave * 4 + (lane >> 4);            // + j*32
    const int sw0 = (c16 ^ (R0 & 7)) << 3;            // j=0: R&7 = R0&7
    const int sw1 = (c16 ^ ((R0 & 7))) << 3;          // j=1: rows +32 (== mod 8)

    const short* abase = h_in + (size_t)(m0 + R0) * 1024;
    const short* bbase = Whh  + (size_t)(n0 + R0) * 1024;

    // ---- prologue: stage chunk 0 (A,B) + Z tile, then one barrier ----
    gll16(abase + sw0,                 (char*)&As[0][0] + (wave * 4) * 256);
    gll16(abase + 32 * 1024 + sw1,     (char*)&As[0][0] + (32 + wave * 4) * 256);
    gll16(bbase + sw0,                 (char*)&Bs[0][0] + (wave * 4) * 256);
    gll16(bbase + 32 * 1024 + sw1,     (char*)&Bs[0][0] + (32 + wave * 4) * 256);
    {
        int zr = wave * 8 + (lane >> 3);
        gll16(Z + ((size_t)t << 20) + (size_t)(m0 + zr) * 1024 + n0 + ((lane & 7) << 3),
              (char*)Zs + wave * 1024);
    }
    __syncthreads();

    f32x4 acc0 = (f32x4)0.0f, acc1 = (f32x4)0.0f;
    const int arow0 = (wm * 32 + r) * 128;
    const int arow1 = (wm * 32 + 16 + r) * 128;
    const int brow  = (wn * 16 + r) * 128;
    const int axor  = r & 7;

    for (int kt = 0; kt < 8; ++kt) {
        const int cur = kt & 1;
        if (kt < 7) {                     // issue next-chunk staging, hidden under compute
            const int nk = (kt + 1) * 128;
            const int nb = cur ^ 1;
            gll16(abase + nk + sw0,             (char*)&As[nb][0] + (wave * 4) * 256);
            gll16(abase + 32 * 1024 + nk + sw1, (char*)&As[nb][0] + (32 + wave * 4) * 256);
            gll16(bbase + nk + sw0,             (char*)&Bs[nb][0] + (wave * 4) * 256);
            gll16(bbase + 32 * 1024 + nk + sw1, (char*)&Bs[nb][0] + (32 + wave * 4) * 256);
        }
        #pragma unroll
        for (int ks = 0; ks < 4; ++ks) {
            const int co = (((ks * 4 + q) ^ axor) << 3);
            bf16x8 a0 = *(const bf16x8*)&As[cur][arow0 + co];
            bf16x8 a1 = *(const bf16x8*)&As[cur][arow1 + co];
            bf16x8 b  = *(const bf16x8*)&Bs[cur][brow + co];
            acc0 = __builtin_amdgcn_mfma_f32_16x16x32_bf16(a0, b, acc0, 0, 0, 0);
            acc1 = __builtin_amdgcn_mfma_f32_16x16x32_bf16(a1, b, acc1, 0, 0, 0);
        }
        __syncthreads();                  // drains vmcnt (next chunk resident) + lgkm
    }

    // ---- epilogue: +Z, tanh -> swizzled C in LDS (reuse As), coalesced stores ----
    short* Csh = &As[0][0];               // 8 KB needed, 32 KB available
    const int col = wn * 16 + r;
    const int cc = col >> 3, rem = col & 7;
    #pragma unroll
    for (int mi = 0; mi < 2; mi++) {
        const f32x4 a = mi ? acc1 : acc0;
        #pragma unroll
        for (int rr = 0; rr < 4; rr++) {
            int row = wm * 32 + mi * 16 + q * 4 + rr;
            float z = bf2f(Zs[row * 64 + col]);
            Csh[row * 64 + ((cc ^ (row & 7)) << 3) + rem] = f2bf(tanh_fast(a[rr] + z));
        }
    }
    __syncthreads();
    {
        int orow = tid >> 3, ochunk = tid & 7;
        int orc = ochunk ^ (orow & 7);
        uint4 v = *(const uint4*)&Csh[orow * 64 + orc * 8];
        *(uint4*)(h_out + (size_t)(m0 + orow) * 1024 + n0 + ochunk * 8) = v;
    }
}

// ---------- head: p[b] = sigmoid(h . W_out + b_out), wave-per-row ----------
__global__ __launch_bounds__(256) void head_kernel(const short* __restrict__ h,
                                                   const float* __restrict__ W_out,
                                                   const float* __restrict__ b_out,
                                                   float* __restrict__ p) {
    int b    = blockIdx.x * 4 + (threadIdx.x >> 6);
    int lane = threadIdx.x & 63;
    float s = 0.f;
    for (int k = lane; k < 1024; k += 64)
        s += bf2f(h[(size_t)b * 1024 + k]) * W_out[k];
    #pragma unroll
    for (int off = 32; off > 0; off >>= 1) s += __shfl_down(s, off);
    if (lane == 0) p[b] = 1.f / (1.f + __expf(-(s + b_out[0])));
}

// ---------- loss: BCE mean with torch-style log clamp at -100 ----------
__global__ __launch_bounds__(1024) void loss_kernel(const float* __restrict__ p,
                                                    const float* __restrict__ y,
                                                    float* __restrict__ loss) {
    __shared__ float red[1024];
    int b = threadIdx.x;
    float pv = p[b];
    float yb = (y[b] >= 1e-5f) ? 1.f : 0.f;
    float lp = fmaxf(logf(pv), -100.f);
    float l1 = fmaxf(log1pf(-pv), -100.f);
    red[b] = yb * lp + (1.f - yb) * l1;
    __syncthreads();
    for (int s = 512; s > 0; s >>= 1) {
        if (b < s) red[b] += red[b + s];
        __syncthreads();
    }
    if (b == 0) loss[0] = -red[0] / 1024.f;
}

// ---------- launch ----------
extern "C" void kernel_launch(void* const* d_in, const int* in_sizes, int n_in,
                              void* d_out, int out_size, void* d_ws, size_t ws_size,
                              hipStream_t stream) {
    const float* av    = (const float*)d_in[3];
    const float* y     = (const float*)d_in[4];
    const float* W_ih  = (const float*)d_in[5];
    const float* b_ih  = (const float*)d_in[6];
    const float* W_hh  = (const float*)d_in[7];
    const float* b_hh  = (const float*)d_in[8];
    const float* W_out = (const float*)d_in[9];
    const float* b_out = (const float*)d_in[10];
    float* out = (float*)d_out;                      // [0]=loss, [1..1024]=p

    char* ws = (char*)d_ws;
    short* Wih_bf = (short*)ws;                      // 2 MB
    short* Whh_bf = (short*)(ws + (2u << 20));       // 2 MB
    float* bsum   = (float*)(ws + (4u << 20));       // 4 KB
    short* hb0    = (short*)(ws + (5u << 20));       // 2 MB
    short* hb1    = (short*)(ws + (7u << 20));       // 2 MB
    short* Z      = (short*)(ws + (9u << 20));       // 128 MB: [64][1024][1024] bf16
    short* X      = (short*)(ws + (137u << 20));     // 128 MB: bf16 av, scan-row order

    pack_w<<<512, 256, 0, stream>>>(W_ih, Wih_bf);
    pack_w<<<512, 256, 0, stream>>>(W_hh, Whh_bf);
    prep_b<<<1, 1024, 0, stream>>>(b_ih, b_hh, bsum);

    bool bigws = ws_size >= ((size_t)266 << 20);

    short* hbuf[2] = { hb0, hb1 };
    if (bigws) {
        conv_av<<<32768, 256, 0, stream>>>(av, X);
        zgemm2<<<4096, 256, 0, stream>>>(X, Wih_bf, bsum, Z);
        t0_kernel<<<512, 256, 0, stream>>>(Z, hb1);
        for (int t = 1; t < 64; ++t)
            step3<<<256, 512, 0, stream>>>(Whh_bf, Z, hbuf[t & 1], hbuf[(t + 1) & 1], t);
    } else {
        zgemm<<<dim3(8, 512), 256, 0, stream>>>(av, Wih_bf, bsum, Z);
        t0_kernel<<<512, 256, 0, stream>>>(Z, hb1);
        for (int t = 1; t < 64; ++t)
            step_kernel<<<dim3(16, 16), 512, 0, stream>>>(Whh_bf, Z, hbuf[t & 1], hbuf[(t + 1) & 1], t);
    }
    // t=63 writes hb0

    head_kernel<<<256, 256, 0, stream>>>(hb0, W_out, b_out, out + 1);
    loss_kernel<<<1, 1024, 0, stream>>>(out + 1, y, out);
}